// Round 13
// baseline (53.212 us; speedup 1.0000x reference)
//
#include <hip/hip_runtime.h>
#include <math.h>

#define MA 64
#define ME 256
#define DM 256
#define DQK 32
#define ENVSTRIDE (MA * ME)            // 16384 floats per env
#define MASKVAL -998244352.0f          // bf16-rounded -1e9 (matches reference)
#define QK_SCALE 0.17677669529663687f  // 1/sqrt(32)
#define KSTR 40                        // LDS row stride in ushorts (80B)

typedef __attribute__((ext_vector_type(8))) short bf16x8;
typedef __attribute__((ext_vector_type(4))) float f32x4;
typedef unsigned short u16;

__device__ __forceinline__ int lb(const int* __restrict__ a, int n, int v){
  int lo = 0, hi = n;
  while (lo < hi){ int mid = (lo + hi) >> 1; if (a[mid] < v) lo = mid + 1; else hi = mid; }
  return lo;
}
// round-to-nearest-even f32 -> bf16 (validated rounds 8-12)
__device__ __forceinline__ unsigned pk2bf(float lo, float hi){
  unsigned ul = __float_as_uint(lo); ul = ul + 0x7FFFu + ((ul >> 16) & 1u);
  unsigned uh = __float_as_uint(hi); uh = uh + 0x7FFFu + ((uh >> 16) & 1u);
  return (ul >> 16) | (uh & 0xFFFF0000u);
}
__device__ __forceinline__ u16 f2bu(float f){
  unsigned u = __float_as_uint(f);
  return (u16)((u + 0x7FFFu + ((u >> 16) & 1u)) >> 16);
}

// ===== K0: pack Wk|Wq into bf16 MFMA-fragment order into d_ws (layout validated r10-r12) =====
__global__ __launch_bounds__(256)
void pack_w(const float* __restrict__ Wk, const float* __restrict__ Wq,
            unsigned* __restrict__ wfr_g){
  const int base = blockIdx.x * 512 + threadIdx.x;
  #pragma unroll
  for (int ii = 0; ii < 2; ++ii) {
    const int i = base + ii * 256;
    const int p = i & 3, ln = (i >> 2) & 63, nt = (i >> 8) & 1, kk = (i >> 9) & 7, wh = i >> 12;
    const int k0  = kk * 32 + (ln >> 4) * 8 + 2 * p;
    const int col = nt * 16 + (ln & 15);
    const float* W = wh ? Wq : Wk;
    wfr_g[i] = pk2bf(W[(size_t)k0 * DQK + col], W[(size_t)(k0 + 1) * DQK + col]);
  }
}

// stage one 16-row tile (16KB) into LDS via global_load_lds; source XOR-swizzled (rule 21)
__device__ __forceinline__ void stage_tile(const float* __restrict__ x, int idxv,
                                           int lane, float* sb){
  #pragma unroll
  for (int s = 0; s < 16; ++s) {
    const int row = __shfl(idxv, s);
    const char* gp = (const char*)(x + (size_t)row * DM) + ((lane * 16) ^ ((s & 7) << 4));
    __builtin_amdgcn_global_load_lds(
        (const __attribute__((address_space(1))) void*)gp,
        (__attribute__((address_space(3))) void*)(sb + s * 256),
        16, 0, 0);
  }
}

// compute one staged tile: swizzled LDS read -> pack -> 16 MFMA -> bf16 scatter to kb/qsm
__device__ __forceinline__ void compute_tile(const float* sb, int lr, int lq,
                                             const bf16x8 (&bfr)[8][2], float bv0, float bv1,
                                             int rbase, int len, u16* __restrict__ dst){
  const char* sbB = (const char*)sb + (size_t)lr * 1024;
  const int sw = (lr & 7) << 4;
  f32x4 a0 = {bv0, bv0, bv0, bv0}, a1 = {bv1, bv1, bv1, bv1};
  #pragma unroll
  for (int kk = 0; kk < 8; ++kk) {
    const int p0 = kk * 128 + lq * 32;
    const float4 c0 = *(const float4*)(sbB + ((p0)      ^ sw));
    const float4 c1 = *(const float4*)(sbB + ((p0 + 16) ^ sw));
    union { unsigned u[4]; bf16x8 v; } fa;
    fa.u[0] = pk2bf(c0.x, c0.y); fa.u[1] = pk2bf(c0.z, c0.w);
    fa.u[2] = pk2bf(c1.x, c1.y); fa.u[3] = pk2bf(c1.z, c1.w);
    a0 = __builtin_amdgcn_mfma_f32_16x16x32_bf16(fa.v, bfr[kk][0], a0, 0, 0, 0);
    a1 = __builtin_amdgcn_mfma_f32_16x16x32_bf16(fa.v, bfr[kk][1], a1, 0, 0, 0);
  }
  #pragma unroll
  for (int reg = 0; reg < 4; ++reg) {
    const int row = rbase + 4 * lq + reg;
    if (row < len) {
      dst[row * KSTR + lr]      = f2bu(a0[reg]);
      dst[row * KSTR + 16 + lr] = f2bu(a1[reg]);
    }
  }
}

// ===== K1: fused per-env kernel; async-staged gather pipeline (counted vmcnt) =====
__global__ __launch_bounds__(256)
void fused_env(const float* __restrict__ x,
               const float* __restrict__ bq, const float* __restrict__ bk,
               const int* __restrict__ actors, const int* __restrict__ qindices,
               const int* __restrict__ actees, const int* __restrict__ kindices,
               const int* __restrict__ prev_actions,
               const unsigned* __restrict__ wfr_g,
               int A, int E, float* __restrict__ out)
{
  __shared__ float stg[4][2][4096];   // 128 KB: per-wave double-buffered 16-row staging
  __shared__ u16 kb[ME * KSTR];       //  20 KB bf16 keys
  __shared__ u16 qsm[MA * KSTR];      //   5 KB bf16 queries
  __shared__ int srange[4];

  const int t = threadIdx.x, b = blockIdx.x;
  const int lane = t & 63, w = t >> 6;
  const int lr = lane & 15, lq = lane >> 4;

  if (t < 4) {
    const int* arr = (t < 2) ? qindices : kindices;
    const int nn = (t < 2) ? A : E;
    const int vv = (t == 0) ? b * MA : (t == 1) ? (b + 1) * MA
                 : (t == 2) ? b * ME : (b + 1) * ME;
    srange[t] = lb(arr, nn, vv);
  }
  __syncthreads();
  const int qstart = srange[0], qlen = srange[1] - srange[0];
  const int kstart = srange[2], klen = srange[3] - srange[2];

  // W fragments held in registers (validated layout)
  bf16x8 bfrK[8][2], bfrQ[8][2];
  {
    const unsigned* fbK = wfr_g + lane * 4;
    const unsigned* fbQ = wfr_g + 4096 + lane * 4;
    #pragma unroll
    for (int kk = 0; kk < 8; ++kk) {
      bfrK[kk][0] = *(const bf16x8*)(fbK + kk * 512);
      bfrK[kk][1] = *(const bf16x8*)(fbK + kk * 512 + 256);
      bfrQ[kk][0] = *(const bf16x8*)(fbQ + kk * 512);
      bfrQ[kk][1] = *(const bf16x8*)(fbQ + kk * 512 + 256);
    }
  }
  const float bkv0 = bk[lr], bkv1 = bk[16 + lr];
  const float bqv0 = bq[lr], bqv1 = bq[16 + lr];

  const int kt = (klen + 15) >> 4;
  const int qt = (qlen + 15) >> 4;
  const int nt_ = kt + qt;
  const int nw = (nt_ > w) ? ((nt_ - w + 3) >> 2) : 0;   // tiles for this wave (<=5)

  // preload ALL tile gather-indices up front (unconditional issue -> exact vmcnt counting)
  int idxv[6];
  #pragma unroll
  for (int tt = 0; tt < 6; ++tt) {
    const int ic  = min(w + 4 * tt, nt_ - 1);
    const bool isk = ic < kt;
    const int rbase = (isk ? ic : ic - kt) << 4;
    const int len   = isk ? klen : qlen;
    const int start = isk ? kstart : qstart;
    const int* gi   = isk ? actees : actors;
    idxv[tt] = (lane < 16) ? gi[start + min(rbase + lane, len - 1)] : 0;
  }

  // software pipeline: stage(tt) || compute(tt-1); 16KB stays in flight across compute
  #pragma unroll
  for (int tt = 0; tt < 6; ++tt) {
    if (tt < nw)
      stage_tile(x, idxv[tt], lane, &stg[w][tt & 1][0]);           // 16 vmem ops
    if (tt >= 1 && (tt - 1) < nw) {
      if (tt < nw) { asm volatile("s_waitcnt vmcnt(16)" ::: "memory"); }
      else         { asm volatile("s_waitcnt vmcnt(0)"  ::: "memory"); }
      const int ip = w + 4 * (tt - 1);
      const bool pk = ip < kt;
      const int rb = (pk ? ip : ip - kt) << 4;
      if (pk) compute_tile(&stg[w][(tt - 1) & 1][0], lr, lq, bfrK, bkv0, bkv1, rb, klen, kb);
      else    compute_tile(&stg[w][(tt - 1) & 1][0], lr, lq, bfrQ, bqv0, bqv1, rb, qlen, qsm);
    }
  }
  __syncthreads();

  // ---- logits + softmax: wave w owns q rows 16w..16w+15 (validated r9/r10) ----
  float* out_lg = out + (size_t)3 * A + (size_t)b * ENVSTRIDE;
  const int row0 = 16 * w;

  if (row0 >= qlen) {          // fully padded rows: MASKVAL fill
    const float4 mv = make_float4(MASKVAL, MASKVAL, MASKVAL, MASKVAL);
    float4* o4 = (float4*)out_lg;
    #pragma unroll
    for (int rr = 0; rr < 16; ++rr) o4[(row0 + rr) * 64 + lane] = mv;
    return;
  }

  const bf16x8 afr = *(const bf16x8*)&qsm[(row0 + lr) * KSTR + lq * 8];
  f32x4 acc[16];
  #pragma unroll
  for (int nt = 0; nt < 16; ++nt) {
    const bf16x8 bfr2 = *(const bf16x8*)&kb[(16 * nt + lr) * KSTR + lq * 8];
    f32x4 z = {0.f, 0.f, 0.f, 0.f};
    acc[nt] = __builtin_amdgcn_mfma_f32_16x16x32_bf16(afr, bfr2, z, 0, 0, 0);
  }

  int par[4];
  float m[4], spa[4], es[4], ts[4];
  #pragma unroll
  for (int reg = 0; reg < 4; ++reg) {
    const int r = row0 + 4 * lq + reg;
    par[reg] = (r < qlen) ? (prev_actions[qstart + r] & (ME - 1)) : -1;
    m[reg] = MASKVAL; spa[reg] = MASKVAL; es[reg] = 0.f; ts[reg] = 0.f;
  }

  #pragma unroll
  for (int nt = 0; nt < 16; ++nt) {
    const int col = 16 * nt + lr;
    const bool kv = (col < klen);
    #pragma unroll
    for (int reg = 0; reg < 4; ++reg) {
      const float d = kv ? acc[nt][reg] * QK_SCALE : MASKVAL;
      acc[nt][reg] = d;
      m[reg] = fmaxf(m[reg], d);
      if (col == par[reg]) spa[reg] = d;
    }
  }
  #pragma unroll
  for (int off = 1; off < 16; off <<= 1) {
    #pragma unroll
    for (int reg = 0; reg < 4; ++reg) {
      m[reg]   = fmaxf(m[reg],   __shfl_xor(m[reg],   off));
      spa[reg] = fmaxf(spa[reg], __shfl_xor(spa[reg], off));
    }
  }
  #pragma unroll
  for (int nt = 0; nt < 16; ++nt) {
    #pragma unroll
    for (int reg = 0; reg < 4; ++reg) {
      const float dd = acc[nt][reg] - m[reg];
      if (dd > -80.f) { const float e = __expf(dd); es[reg] += e; ts[reg] += e * dd; }
    }
  }
  #pragma unroll
  for (int off = 1; off < 16; off <<= 1) {
    #pragma unroll
    for (int reg = 0; reg < 4; ++reg) {
      es[reg] += __shfl_xor(es[reg], off);
      ts[reg] += __shfl_xor(ts[reg], off);
    }
  }

  #pragma unroll
  for (int nt = 0; nt < 16; ++nt) {
    #pragma unroll
    for (int reg = 0; reg < 4; ++reg) {
      const int r = row0 + 4 * lq + reg;
      out_lg[r * ME + 16 * nt + lr] = (r < qlen) ? acc[nt][reg] : MASKVAL;
    }
  }
  if (lr == 0) {
    #pragma unroll
    for (int reg = 0; reg < 4; ++reg) {
      const int r = row0 + 4 * lq + reg;
      if (r < qlen) {
        const float lS = __logf(fmaxf(es[reg], 1e-30f));
        out[qstart + r]         = (float)par[reg];
        out[A + qstart + r]     = spa[reg] - m[reg] - lS;
        out[2 * A + qstart + r] = lS - ts[reg] / es[reg];
      }
    }
  }
}

extern "C" void kernel_launch(void* const* d_in, const int* in_sizes, int n_in,
                              void* d_out, int out_size, void* d_ws, size_t ws_size,
                              hipStream_t stream) {
  const float* x  = (const float*)d_in[0];
  const float* Wq = (const float*)d_in[1];
  const float* bq = (const float*)d_in[2];
  const float* Wk = (const float*)d_in[3];
  const float* bk = (const float*)d_in[4];
  const int* actors       = (const int*)d_in[5];
  const int* qindices     = (const int*)d_in[6];
  const int* actees       = (const int*)d_in[7];
  const int* kindices     = (const int*)d_in[8];
  const int* prev_actions = (const int*)d_in[9];

  const int A = in_sizes[5];
  const int E = in_sizes[7];
  const int B = (out_size - 3 * A) / ENVSTRIDE;
  if (B <= 0) return;

  unsigned* wfr_g = (unsigned*)d_ws;   // 32 KB scratch for packed W fragments

  pack_w<<<dim3(16), dim3(256), 0, stream>>>(Wk, Wq, wfr_g);
  fused_env<<<dim3(B), dim3(256), 0, stream>>>(
      x, bq, bk, actors, qindices, actees, kindices, prev_actions,
      wfr_g, A, E, (float*)d_out);
}

// Round 14
// 45.011 us; speedup vs baseline: 1.1822x; 1.1822x over previous
//
#include <hip/hip_runtime.h>
#include <math.h>

#define MA 64
#define ME 256
#define DM 256
#define DQK 32
#define ENVSTRIDE (MA * ME)            // 16384 floats per env
#define MASKVAL -998244352.0f          // bf16-rounded -1e9 (matches reference)
#define QK_SCALE 0.17677669529663687f  // 1/sqrt(32)
#define KSTR 40                        // LDS row stride in ushorts (80B)

typedef __attribute__((ext_vector_type(8))) short bf16x8;
typedef __attribute__((ext_vector_type(4))) float f32x4;
typedef unsigned short u16;

__device__ __forceinline__ int lb(const int* __restrict__ a, int n, int v){
  int lo = 0, hi = n;
  while (lo < hi){ int mid = (lo + hi) >> 1; if (a[mid] < v) lo = mid + 1; else hi = mid; }
  return lo;
}
// round-to-nearest-even f32 -> bf16 (validated rounds 8-13)
__device__ __forceinline__ unsigned pk2bf(float lo, float hi){
  unsigned ul = __float_as_uint(lo); ul = ul + 0x7FFFu + ((ul >> 16) & 1u);
  unsigned uh = __float_as_uint(hi); uh = uh + 0x7FFFu + ((uh >> 16) & 1u);
  return (ul >> 16) | (uh & 0xFFFF0000u);
}
__device__ __forceinline__ u16 f2bu(float f){
  unsigned u = __float_as_uint(f);
  return (u16)((u + 0x7FFFu + ((u >> 16) & 1u)) >> 16);
}

// ===== K0: pack Wk|Wq into bf16 MFMA-fragment order into d_ws (layout validated r10-r13) =====
__global__ __launch_bounds__(256)
void pack_w(const float* __restrict__ Wk, const float* __restrict__ Wq,
            unsigned* __restrict__ wfr_g){
  const int base = blockIdx.x * 512 + threadIdx.x;
  #pragma unroll
  for (int ii = 0; ii < 2; ++ii) {
    const int i = base + ii * 256;
    const int p = i & 3, ln = (i >> 2) & 63, nt = (i >> 8) & 1, kk = (i >> 9) & 7, wh = i >> 12;
    const int k0  = kk * 32 + (ln >> 4) * 8 + 2 * p;
    const int col = nt * 16 + (ln & 15);
    const float* W = wh ? Wq : Wk;
    wfr_g[i] = pk2bf(W[(size_t)k0 * DQK + col], W[(size_t)(k0 + 1) * DQK + col]);
  }
}

// ===== K1: fused per-env kernel (r10 structure; W-frags from global -> 25KB LDS) =====
__global__ __launch_bounds__(256)
void fused_env(const float* __restrict__ x,
               const float* __restrict__ bq, const float* __restrict__ bk,
               const int* __restrict__ actors, const int* __restrict__ qindices,
               const int* __restrict__ actees, const int* __restrict__ kindices,
               const int* __restrict__ prev_actions,
               const unsigned* __restrict__ wfr_g,
               int A, int E, float* __restrict__ out)
{
  __shared__ u16 kb[ME * KSTR];    // 20 KB bf16 keys
  __shared__ u16 qsm[MA * KSTR];   //  5 KB bf16 queries
  __shared__ int srange[4];

  const int t = threadIdx.x, b = blockIdx.x;
  if (t < 4) {
    const int* arr = (t < 2) ? qindices : kindices;
    const int nn = (t < 2) ? A : E;
    const int vv = (t == 0) ? b * MA : (t == 1) ? (b + 1) * MA
                 : (t == 2) ? b * ME : (b + 1) * ME;
    srange[t] = lb(arr, nn, vv);
  }
  __syncthreads();

  const int qstart = srange[0], qlen = srange[1] - srange[0];
  const int kstart = srange[2], klen = srange[3] - srange[2];

  const int lane = t & 63, w = t >> 6;
  const int lr = lane & 15, lq = lane >> 4;

  const float bkv0 = bk[lr], bkv1 = bk[16 + lr];
  const float bqv0 = bq[lr], bqv1 = bq[16 + lr];

  // ---- projection: merged K+Q tile list, wave-strided (datapath validated r9-r13) ----
  const int kt = (klen + 15) >> 4;
  const int qt = (qlen + 15) >> 4;
  const int ntiles = kt + qt;

  for (int i = w; i < ntiles; i += 4) {
    const bool isk = (i < kt);
    const int  rbase = isk ? (i << 4) : ((i - kt) << 4);
    const int  len   = isk ? klen : qlen;
    const int  start = isk ? kstart : qstart;
    const int* gath  = isk ? actees : actors;
    u16*       dst   = isk ? kb : qsm;
    const unsigned* fb = wfr_g + (isk ? 0 : 4096) + lane * 4;

    // per-tile W fragments from packed global (16 coalesced 16B loads, L2/L3-hot)
    bf16x8 bfr[8][2];
    #pragma unroll
    for (int kk = 0; kk < 8; ++kk) {
      bfr[kk][0] = *(const bf16x8*)(fb + kk * 512);
      bfr[kk][1] = *(const bf16x8*)(fb + kk * 512 + 256);
    }

    const int arow = start + min(rbase + lr, len - 1);
    const float* xr = x + (size_t)gath[arow] * DM + lq * 8;

    float4 cx[16];
    #pragma unroll
    for (int kk = 0; kk < 8; ++kk) {
      cx[2*kk]   = *(const float4*)(xr + kk * 32);
      cx[2*kk+1] = *(const float4*)(xr + kk * 32 + 4);
    }

    const float v0 = isk ? bkv0 : bqv0, v1 = isk ? bkv1 : bqv1;
    f32x4 a0 = {v0, v0, v0, v0}, a1 = {v1, v1, v1, v1};
    #pragma unroll
    for (int kk = 0; kk < 8; ++kk) {
      union { unsigned u[4]; bf16x8 v; } fa;
      fa.u[0] = pk2bf(cx[2*kk].x,   cx[2*kk].y);
      fa.u[1] = pk2bf(cx[2*kk].z,   cx[2*kk].w);
      fa.u[2] = pk2bf(cx[2*kk+1].x, cx[2*kk+1].y);
      fa.u[3] = pk2bf(cx[2*kk+1].z, cx[2*kk+1].w);
      a0 = __builtin_amdgcn_mfma_f32_16x16x32_bf16(fa.v, bfr[kk][0], a0, 0, 0, 0);
      a1 = __builtin_amdgcn_mfma_f32_16x16x32_bf16(fa.v, bfr[kk][1], a1, 0, 0, 0);
    }
    // D: col = lane&15, row = 4*(lane>>4)+reg (validated)
    #pragma unroll
    for (int reg = 0; reg < 4; ++reg) {
      const int row = rbase + 4 * lq + reg;
      if (row < len) {
        dst[row * KSTR + lr]      = f2bu(a0[reg]);
        dst[row * KSTR + 16 + lr] = f2bu(a1[reg]);
      }
    }
  }
  __syncthreads();

  // ---- logits + softmax: wave w owns q rows 16w..16w+15 (validated r9/r10) ----
  float* out_lg = out + (size_t)3 * A + (size_t)b * ENVSTRIDE;
  const int row0 = 16 * w;

  if (row0 >= qlen) {          // fully padded rows: MASKVAL fill
    const float4 mv = make_float4(MASKVAL, MASKVAL, MASKVAL, MASKVAL);
    float4* o4 = (float4*)out_lg;
    #pragma unroll
    for (int rr = 0; rr < 16; ++rr) o4[(row0 + rr) * 64 + lane] = mv;
    return;
  }

  const bf16x8 afr = *(const bf16x8*)&qsm[(row0 + lr) * KSTR + lq * 8];
  f32x4 acc[16];
  #pragma unroll
  for (int nt = 0; nt < 16; ++nt) {
    const bf16x8 bfr2 = *(const bf16x8*)&kb[(16 * nt + lr) * KSTR + lq * 8];
    f32x4 z = {0.f, 0.f, 0.f, 0.f};
    acc[nt] = __builtin_amdgcn_mfma_f32_16x16x32_bf16(afr, bfr2, z, 0, 0, 0);
  }

  int par[4];
  float m[4], spa[4], es[4], ts[4];
  #pragma unroll
  for (int reg = 0; reg < 4; ++reg) {
    const int r = row0 + 4 * lq + reg;
    par[reg] = (r < qlen) ? (prev_actions[qstart + r] & (ME - 1)) : -1;
    m[reg] = MASKVAL; spa[reg] = MASKVAL; es[reg] = 0.f; ts[reg] = 0.f;
  }

  #pragma unroll
  for (int nt = 0; nt < 16; ++nt) {
    const int col = 16 * nt + lr;
    const bool kv = (col < klen);
    #pragma unroll
    for (int reg = 0; reg < 4; ++reg) {
      const float d = kv ? acc[nt][reg] * QK_SCALE : MASKVAL;
      acc[nt][reg] = d;
      m[reg] = fmaxf(m[reg], d);
      if (col == par[reg]) spa[reg] = d;
    }
  }
  #pragma unroll
  for (int off = 1; off < 16; off <<= 1) {
    #pragma unroll
    for (int reg = 0; reg < 4; ++reg) {
      m[reg]   = fmaxf(m[reg],   __shfl_xor(m[reg],   off));
      spa[reg] = fmaxf(spa[reg], __shfl_xor(spa[reg], off));
    }
  }
  #pragma unroll
  for (int nt = 0; nt < 16; ++nt) {
    #pragma unroll
    for (int reg = 0; reg < 4; ++reg) {
      const float dd = acc[nt][reg] - m[reg];
      if (dd > -80.f) { const float e = __expf(dd); es[reg] += e; ts[reg] += e * dd; }
    }
  }
  #pragma unroll
  for (int off = 1; off < 16; off <<= 1) {
    #pragma unroll
    for (int reg = 0; reg < 4; ++reg) {
      es[reg] += __shfl_xor(es[reg], off);
      ts[reg] += __shfl_xor(ts[reg], off);
    }
  }

  #pragma unroll
  for (int nt = 0; nt < 16; ++nt) {
    #pragma unroll
    for (int reg = 0; reg < 4; ++reg) {
      const int r = row0 + 4 * lq + reg;
      out_lg[r * ME + 16 * nt + lr] = (r < qlen) ? acc[nt][reg] : MASKVAL;
    }
  }
  if (lr == 0) {
    #pragma unroll
    for (int reg = 0; reg < 4; ++reg) {
      const int r = row0 + 4 * lq + reg;
      if (r < qlen) {
        const float lS = __logf(fmaxf(es[reg], 1e-30f));
        out[qstart + r]         = (float)par[reg];
        out[A + qstart + r]     = spa[reg] - m[reg] - lS;
        out[2 * A + qstart + r] = lS - ts[reg] / es[reg];
      }
    }
  }
}

extern "C" void kernel_launch(void* const* d_in, const int* in_sizes, int n_in,
                              void* d_out, int out_size, void* d_ws, size_t ws_size,
                              hipStream_t stream) {
  const float* x  = (const float*)d_in[0];
  const float* Wq = (const float*)d_in[1];
  const float* bq = (const float*)d_in[2];
  const float* Wk = (const float*)d_in[3];
  const float* bk = (const float*)d_in[4];
  const int* actors       = (const int*)d_in[5];
  const int* qindices     = (const int*)d_in[6];
  const int* actees       = (const int*)d_in[7];
  const int* kindices     = (const int*)d_in[8];
  const int* prev_actions = (const int*)d_in[9];

  const int A = in_sizes[5];
  const int E = in_sizes[7];
  const int B = (out_size - 3 * A) / ENVSTRIDE;
  if (B <= 0) return;

  unsigned* wfr_g = (unsigned*)d_ws;   // 32 KB scratch for packed W fragments

  pack_w<<<dim3(16), dim3(256), 0, stream>>>(Wk, Wq, wfr_g);
  fused_env<<<dim3(B), dim3(256), 0, stream>>>(
      x, bq, bk, actors, qindices, actees, kindices, prev_actions,
      wfr_g, A, E, (float*)d_out);
}